// Round 1
// baseline (4273.656 us; speedup 1.0000x reference)
//
#include <hip/hip_runtime.h>
#include <math.h>

#define NN 100000
#define NE 1600000
#define DD 128     // D_IN == D_OUT

// ---------------------------------------------------------------------------
// Phase 1a: init agg (stored in d_out) to -inf so empty nodes are detectable.
// ---------------------------------------------------------------------------
__global__ void init_neg_inf_kernel(float4* __restrict__ out, int n4) {
    int i = blockIdx.x * blockDim.x + threadIdx.x;
    if (i < n4) {
        const float ni = -INFINITY;
        out[i] = make_float4(ni, ni, ni, ni);
    }
}

// ---------------------------------------------------------------------------
// Phase 1b: edge-parallel segment max. 32 lanes per edge, 4 feats/lane.
// Float atomic max via int/uint ordering trick (inputs finite, never NaN):
//   v >= 0: int ordering == float ordering, and any non-neg int repr beats
//           any negative one.
//   v <  0: uint ordering is reversed float ordering among negatives, and
//           any negative uint repr (>=0x80000000) loses min() to non-negs.
// Both ops are monotone non-decreasing in float order => result = max.
// ---------------------------------------------------------------------------
__device__ __forceinline__ void atomic_max_f32(float* addr, float v) {
    if (v >= 0.0f) atomicMax((int*)addr, __float_as_int(v));
    else           atomicMin((unsigned int*)addr, __float_as_uint(v));
}

__global__ __launch_bounds__(256) void edge_max_kernel(
        const float* __restrict__ H,
        const int* __restrict__ src,
        const int* __restrict__ dst,
        float* __restrict__ agg) {
    int gtid = blockIdx.x * blockDim.x + threadIdx.x;
    int e = gtid >> 5;
    if (e >= NE) return;
    int c = (gtid & 31) << 2;       // feature offset, 0..124
    int s = src[e];
    int d = dst[e];
    float4 v = *(const float4*)(H + (size_t)d * DD + c);
    float* base = agg + (size_t)s * DD + c;
    atomic_max_f32(base + 0, v.x);
    atomic_max_f32(base + 1, v.y);
    atomic_max_f32(base + 2, v.z);
    atomic_max_f32(base + 3, v.w);
}

// ---------------------------------------------------------------------------
// Phase 2: out[i,o] = b[o] + sum_d H[i,d]*W[o,d] + sum_d neigh[i,d]*W[o,128+d]
// where neigh = (agg == -inf ? 0 : agg), agg stored IN-PLACE in `out`.
// In-place is safe: block b reads agg rows [64b, 64b+64) only, and all global
// reads happen before the final __syncthreads that precedes its stores.
// Tile: 64 rows x 128 outs / block (256 thr), 4x8 microtile per thread.
// ---------------------------------------------------------------------------
__global__ __launch_bounds__(256) void sage_matmul_kernel(
        const float* __restrict__ H,
        const float* __restrict__ W,      // [128][256] row-major
        const float* __restrict__ bias,   // [128]
        float* __restrict__ out) {        // in: agg, out: result  [NN][128]
    __shared__ float Xs[64][68];          // +4 pad: float4-aligned, kills conflicts
    __shared__ float Ws[64][132];         // transposed W chunk: Ws[k][o]

    const int t = threadIdx.x;
    const int block_row = blockIdx.x * 64;
    const int tx = t & 15;                // out group: o in [tx*8, tx*8+8)
    const int ty = t >> 4;                // row group: r in [ty*4, ty*4+4)

    float acc[4][8];
#pragma unroll
    for (int r = 0; r < 4; ++r)
#pragma unroll
        for (int o = 0; o < 8; ++o) acc[r][o] = 0.0f;

#pragma unroll
    for (int chunk = 0; chunk < 4; ++chunk) {
        const int k0 = chunk * 64;
        const bool from_agg = (k0 >= 128);
        const int koff = from_agg ? (k0 - 128) : k0;
        const float* xbase = from_agg ? out : H;

        // --- stage X tile: 64 rows x 64 k, coalesced float4 ---
#pragma unroll
        for (int j = 0; j < 4; ++j) {
            int e = j * 256 + t;          // 0..1023
            int r = e >> 4;
            int c = (e & 15) << 2;
            int row = block_row + r;
            float4 v = make_float4(0.f, 0.f, 0.f, 0.f);
            if (row < NN) {
                v = *(const float4*)(xbase + (size_t)row * DD + koff + c);
                if (from_agg) {
                    if (v.x == -INFINITY) v.x = 0.f;
                    if (v.y == -INFINITY) v.y = 0.f;
                    if (v.z == -INFINITY) v.z = 0.f;
                    if (v.w == -INFINITY) v.w = 0.f;
                }
            }
            *(float4*)&Xs[r][c] = v;
        }

        // --- stage W chunk transposed: read W rows coalesced (float4),
        //     scatter into Ws[k][o] ---
#pragma unroll
        for (int j = 0; j < 8; ++j) {
            int e = j * 256 + t;          // 0..2047
            int kc = (e & 15) << 2;       // k within chunk, 0..60
            int o = e >> 4;               // 0..127
            float4 w4 = *(const float4*)(W + o * 256 + k0 + kc);
            Ws[kc + 0][o] = w4.x;
            Ws[kc + 1][o] = w4.y;
            Ws[kc + 2][o] = w4.z;
            Ws[kc + 3][o] = w4.w;
        }
        __syncthreads();

        // --- inner product over this k chunk ---
        for (int k = 0; k < 64; ++k) {
            float xv[4];
#pragma unroll
            for (int r = 0; r < 4; ++r) xv[r] = Xs[ty * 4 + r][k];
            float4 wa = *(const float4*)&Ws[k][tx * 8];
            float4 wb = *(const float4*)&Ws[k][tx * 8 + 4];
            float wv[8] = {wa.x, wa.y, wa.z, wa.w, wb.x, wb.y, wb.z, wb.w};
#pragma unroll
            for (int r = 0; r < 4; ++r)
#pragma unroll
                for (int o = 0; o < 8; ++o)
                    acc[r][o] = fmaf(xv[r], wv[o], acc[r][o]);
        }
        __syncthreads();
    }

    // --- epilogue: bias + store (overwrites agg rows of this block only) ---
    float4 ba = *(const float4*)(bias + tx * 8);
    float4 bb = *(const float4*)(bias + tx * 8 + 4);
#pragma unroll
    for (int r = 0; r < 4; ++r) {
        int row = block_row + ty * 4 + r;
        if (row < NN) {
            float4 oa = make_float4(acc[r][0] + ba.x, acc[r][1] + ba.y,
                                    acc[r][2] + ba.z, acc[r][3] + ba.w);
            float4 ob = make_float4(acc[r][4] + bb.x, acc[r][5] + bb.y,
                                    acc[r][6] + bb.z, acc[r][7] + bb.w);
            *(float4*)(out + (size_t)row * DD + tx * 8) = oa;
            *(float4*)(out + (size_t)row * DD + tx * 8 + 4) = ob;
        }
    }
}

extern "C" void kernel_launch(void* const* d_in, const int* in_sizes, int n_in,
                              void* d_out, int out_size, void* d_ws, size_t ws_size,
                              hipStream_t stream) {
    const float* H   = (const float*)d_in[0];
    const int*   src = (const int*)d_in[1];
    const int*   dst = (const int*)d_in[2];
    const float* W   = (const float*)d_in[3];
    const float* b   = (const float*)d_in[4];
    float* out = (float*)d_out;

    const int n4 = NN * DD / 4;   // 3.2M float4
    init_neg_inf_kernel<<<(n4 + 255) / 256, 256, 0, stream>>>((float4*)out, n4);

    const long long ethreads = (long long)NE * 32;
    edge_max_kernel<<<(int)((ethreads + 255) / 256), 256, 0, stream>>>(H, src, dst, out);

    sage_matmul_kernel<<<(NN + 63) / 64, 256, 0, stream>>>(H, W, b, out);
}

// Round 2
// 593.389 us; speedup vs baseline: 7.2021x; 7.2021x over previous
//
#include <hip/hip_runtime.h>
#include <math.h>

#define NN 100000
#define NE 1600000
#define DD 128     // D_IN == D_OUT

// ---------------------------------------------------------------------------
// d_ws layout (int32 elements):
//   counts  [NN]      at 0
//   offsets [NN+1]    at NN
//   cursor  [NN]      at 2*NN + 4
//   bucket  [NE]      at 3*NN + 8
// Total = (3*NN + 8 + NE) * 4  ~= 7.6 MB
// ---------------------------------------------------------------------------
#define WS_COUNTS  0
#define WS_OFFSETS (NN)
#define WS_CURSOR  (2 * NN + 4)
#define WS_BUCKET  (3 * NN + 8)

__global__ __launch_bounds__(256) void zero_counts_kernel(int* __restrict__ counts) {
    int i = blockIdx.x * blockDim.x + threadIdx.x;
    if (i < NN) counts[i] = 0;
}

__global__ __launch_bounds__(256) void count_kernel(const int* __restrict__ src,
                                                    int* __restrict__ counts) {
    int e = blockIdx.x * blockDim.x + threadIdx.x;
    if (e < NE) atomicAdd(&counts[src[e]], 1);
}

// Single-block exclusive scan of counts[NN] -> offsets[NN+1], copy to cursor.
// Per-wave shfl inclusive scan + LDS wave-total combine; 3 syncs per 1024-tile.
__global__ __launch_bounds__(1024) void scan_kernel(const int* __restrict__ counts,
                                                    int* __restrict__ offsets,
                                                    int* __restrict__ cursor) {
    __shared__ int wsum[16];
    __shared__ int carry_s;
    const int t = threadIdx.x;
    const int lane = t & 63;
    const int w = t >> 6;
    if (t == 0) carry_s = 0;
    __syncthreads();
    for (int base = 0; base < NN; base += 1024) {
        int i = base + t;
        int v = (i < NN) ? counts[i] : 0;
        int incl = v;
#pragma unroll
        for (int off = 1; off < 64; off <<= 1) {
            int y = __shfl_up(incl, off, 64);
            if (lane >= off) incl += y;
        }
        if (lane == 63) wsum[w] = incl;
        __syncthreads();                       // S1: wsum visible
        int wpre = 0;
#pragma unroll
        for (int k = 0; k < 16; ++k) wpre += (k < w) ? wsum[k] : 0;
        int carry = carry_s;
        int excl = carry + wpre + incl - v;
        if (i < NN) { offsets[i] = excl; cursor[i] = excl; }
        __syncthreads();                       // S2: all reads of carry_s/wsum done
        if (t == 1023) carry_s = carry + wpre + incl;
        __syncthreads();                       // S3: carry_s update visible
    }
    if (t == 0) offsets[NN] = carry_s;         // == NE
}

__global__ __launch_bounds__(256) void scatter_kernel(const int* __restrict__ src,
                                                      const int* __restrict__ dst,
                                                      int* __restrict__ cursor,
                                                      int* __restrict__ bucket) {
    int e = blockIdx.x * blockDim.x + threadIdx.x;
    if (e < NE) {
        int pos = atomicAdd(&cursor[src[e]], 1);
        bucket[pos] = dst[e];
    }
}

// ---------------------------------------------------------------------------
// Per-node gather-max: one wave per node, lane covers 2 feats (float2).
// Each neighbor row read is one coalesced 512B wave transaction (LLC-resident).
// 4-wide neighbor unroll for memory-level parallelism. Empty nodes write 0.
// ---------------------------------------------------------------------------
__global__ __launch_bounds__(256) void agg_max_kernel(const float* __restrict__ H,
                                                      const int* __restrict__ offsets,
                                                      const int* __restrict__ bucket,
                                                      float* __restrict__ agg) {
    int wave = (blockIdx.x * blockDim.x + threadIdx.x) >> 6;
    int lane = threadIdx.x & 63;
    if (wave >= NN) return;
    int beg = offsets[wave];
    int end = offsets[wave + 1];
    float2 m = make_float2(0.f, 0.f);
    if (beg < end) {
        m = make_float2(-INFINITY, -INFINITY);
        int j = beg;
        for (; j + 4 <= end; j += 4) {
            int n0 = bucket[j + 0];
            int n1 = bucket[j + 1];
            int n2 = bucket[j + 2];
            int n3 = bucket[j + 3];
            float2 v0 = *(const float2*)(H + (size_t)n0 * DD + lane * 2);
            float2 v1 = *(const float2*)(H + (size_t)n1 * DD + lane * 2);
            float2 v2 = *(const float2*)(H + (size_t)n2 * DD + lane * 2);
            float2 v3 = *(const float2*)(H + (size_t)n3 * DD + lane * 2);
            m.x = fmaxf(m.x, fmaxf(fmaxf(v0.x, v1.x), fmaxf(v2.x, v3.x)));
            m.y = fmaxf(m.y, fmaxf(fmaxf(v0.y, v1.y), fmaxf(v2.y, v3.y)));
        }
        for (; j < end; ++j) {
            int n0 = bucket[j];
            float2 v0 = *(const float2*)(H + (size_t)n0 * DD + lane * 2);
            m.x = fmaxf(m.x, v0.x);
            m.y = fmaxf(m.y, v0.y);
        }
    }
    *(float2*)(agg + (size_t)wave * DD + lane * 2) = m;
}

// ---------------------------------------------------------------------------
// out[i,o] = b[o] + sum_d H[i,d]*W[o,d] + sum_d agg[i,d]*W[o,128+d]
// agg stored IN-PLACE in `out`. Safe: block reads only its own 64 rows, all
// reads precede the final __syncthreads before its stores.
// Tile: 64 rows x 128 outs / block (256 thr), 4x8 microtile per thread.
// ---------------------------------------------------------------------------
__global__ __launch_bounds__(256) void sage_matmul_kernel(
        const float* __restrict__ H,
        const float* __restrict__ W,      // [128][256] row-major
        const float* __restrict__ bias,   // [128]
        float* __restrict__ out) {        // in: agg, out: result  [NN][128]
    __shared__ float Xs[64][68];
    __shared__ float Ws[64][132];

    const int t = threadIdx.x;
    const int block_row = blockIdx.x * 64;
    const int tx = t & 15;                // out group: o in [tx*8, tx*8+8)
    const int ty = t >> 4;                // row group: r in [ty*4, ty*4+4)

    float acc[4][8];
#pragma unroll
    for (int r = 0; r < 4; ++r)
#pragma unroll
        for (int o = 0; o < 8; ++o) acc[r][o] = 0.0f;

#pragma unroll
    for (int chunk = 0; chunk < 4; ++chunk) {
        const int k0 = chunk * 64;
        const bool from_agg = (k0 >= 128);
        const int koff = from_agg ? (k0 - 128) : k0;
        const float* xbase = from_agg ? out : H;

        // stage X tile: 64 rows x 64 k, coalesced float4
#pragma unroll
        for (int j = 0; j < 4; ++j) {
            int e = j * 256 + t;
            int r = e >> 4;
            int c = (e & 15) << 2;
            int row = block_row + r;
            float4 v = make_float4(0.f, 0.f, 0.f, 0.f);
            if (row < NN)
                v = *(const float4*)(xbase + (size_t)row * DD + koff + c);
            *(float4*)&Xs[r][c] = v;
        }

        // stage W chunk transposed: Ws[k][o]
#pragma unroll
        for (int j = 0; j < 8; ++j) {
            int e = j * 256 + t;
            int kc = (e & 15) << 2;
            int o = e >> 4;
            float4 w4 = *(const float4*)(W + o * 256 + k0 + kc);
            Ws[kc + 0][o] = w4.x;
            Ws[kc + 1][o] = w4.y;
            Ws[kc + 2][o] = w4.z;
            Ws[kc + 3][o] = w4.w;
        }
        __syncthreads();

        for (int k = 0; k < 64; ++k) {
            float xv[4];
#pragma unroll
            for (int r = 0; r < 4; ++r) xv[r] = Xs[ty * 4 + r][k];
            float4 wa = *(const float4*)&Ws[k][tx * 8];
            float4 wb = *(const float4*)&Ws[k][tx * 8 + 4];
            float wv[8] = {wa.x, wa.y, wa.z, wa.w, wb.x, wb.y, wb.z, wb.w};
#pragma unroll
            for (int r = 0; r < 4; ++r)
#pragma unroll
                for (int o = 0; o < 8; ++o)
                    acc[r][o] = fmaf(xv[r], wv[o], acc[r][o]);
        }
        __syncthreads();
    }

    float4 ba = *(const float4*)(bias + tx * 8);
    float4 bb = *(const float4*)(bias + tx * 8 + 4);
#pragma unroll
    for (int r = 0; r < 4; ++r) {
        int row = block_row + ty * 4 + r;
        if (row < NN) {
            float4 oa = make_float4(acc[r][0] + ba.x, acc[r][1] + ba.y,
                                    acc[r][2] + ba.z, acc[r][3] + ba.w);
            float4 ob = make_float4(acc[r][4] + bb.x, acc[r][5] + bb.y,
                                    acc[r][6] + bb.z, acc[r][7] + bb.w);
            *(float4*)(out + (size_t)row * DD + tx * 8) = oa;
            *(float4*)(out + (size_t)row * DD + tx * 8 + 4) = ob;
        }
    }
}

extern "C" void kernel_launch(void* const* d_in, const int* in_sizes, int n_in,
                              void* d_out, int out_size, void* d_ws, size_t ws_size,
                              hipStream_t stream) {
    const float* H   = (const float*)d_in[0];
    const int*   src = (const int*)d_in[1];
    const int*   dst = (const int*)d_in[2];
    const float* W   = (const float*)d_in[3];
    const float* b   = (const float*)d_in[4];
    float* out = (float*)d_out;

    int* ws      = (int*)d_ws;
    int* counts  = ws + WS_COUNTS;
    int* offsets = ws + WS_OFFSETS;
    int* cursor  = ws + WS_CURSOR;
    int* bucket  = ws + WS_BUCKET;

    zero_counts_kernel<<<(NN + 255) / 256, 256, 0, stream>>>(counts);
    count_kernel<<<(NE + 255) / 256, 256, 0, stream>>>(src, counts);
    scan_kernel<<<1, 1024, 0, stream>>>(counts, offsets, cursor);
    scatter_kernel<<<(NE + 255) / 256, 256, 0, stream>>>(src, dst, cursor, bucket);

    const long long athreads = (long long)NN * 64;
    agg_max_kernel<<<(int)((athreads + 255) / 256), 256, 0, stream>>>(H, offsets, bucket, out);

    sage_matmul_kernel<<<(NN + 63) / 64, 256, 0, stream>>>(H, W, b, out);
}

// Round 3
// 381.695 us; speedup vs baseline: 11.1965x; 1.5546x over previous
//
#include <hip/hip_runtime.h>
#include <math.h>

#define NN 100000
#define NE 1600000
#define DD 128          // D_IN == D_OUT
#define NB 1563         // ceil(NN / 64) bins of 64 nodes
#define BIN_NODES 64

// ---------------------------------------------------------------------------
// d_ws layout (int32 elements):
//   bin_counts  [NB]        @ 0
//   bin_offsets [NB+1]      @ NB
//   bin_cursor  [NB]        @ 2*NB+2
//   entries     [NE]        @ 3*NB+2   (packed: (src&63)<<17 | dst; dst<2^17)
// total ~ 6.42 MB
// ---------------------------------------------------------------------------
#define WS_COUNTS  0
#define WS_OFFSETS (NB)
#define WS_CURSOR  (2 * NB + 2)
#define WS_ENTRIES (3 * NB + 2)

__global__ __launch_bounds__(256) void zero_bins_kernel(int* __restrict__ counts) {
    int i = blockIdx.x * blockDim.x + threadIdx.x;
    if (i < NB) counts[i] = 0;
}

// LDS-privatized per-bin counting: 1563 local counters, one flush per block.
__global__ __launch_bounds__(256) void bin_count_kernel(const int* __restrict__ src,
                                                        int* __restrict__ bin_counts) {
    __shared__ int cnt[NB];
    for (int i = threadIdx.x; i < NB; i += 256) cnt[i] = 0;
    __syncthreads();
    const int stride = gridDim.x * 256;
    for (int e = blockIdx.x * 256 + threadIdx.x; e < NE; e += stride)
        atomicAdd(&cnt[src[e] >> 6], 1);
    __syncthreads();
    for (int i = threadIdx.x; i < NB; i += 256) {
        int c = cnt[i];
        if (c) atomicAdd(&bin_counts[i], c);
    }
}

// Single-block exclusive scan over NB=1563 bins (2 tiles of 1024).
__global__ __launch_bounds__(1024) void bin_scan_kernel(const int* __restrict__ counts,
                                                        int* __restrict__ offsets,
                                                        int* __restrict__ cursor) {
    __shared__ int wsum[16];
    __shared__ int carry_s;
    const int t = threadIdx.x;
    const int lane = t & 63;
    const int w = t >> 6;
    if (t == 0) carry_s = 0;
    __syncthreads();
    for (int base = 0; base < NB; base += 1024) {
        int i = base + t;
        int v = (i < NB) ? counts[i] : 0;
        int incl = v;
#pragma unroll
        for (int off = 1; off < 64; off <<= 1) {
            int y = __shfl_up(incl, off, 64);
            if (lane >= off) incl += y;
        }
        if (lane == 63) wsum[w] = incl;
        __syncthreads();
        int wpre = 0;
#pragma unroll
        for (int k = 0; k < 16; ++k) wpre += (k < w) ? wsum[k] : 0;
        int carry = carry_s;
        int excl = carry + wpre + incl - v;
        if (i < NB) { offsets[i] = excl; cursor[i] = excl; }
        __syncthreads();
        if (t == 1023) carry_s = carry + wpre + incl;
        __syncthreads();
    }
    if (t == 0) offsets[NB] = carry_s;   // == NE
}

// Partition edges into per-bin segments of packed entries. Per-block per-bin
// appends are contiguous (block reserves a run via one global atomic per bin),
// so writes cluster within bin regions -> far less line amplification than
// the old fully-random scatter.
__global__ __launch_bounds__(256) void partition_kernel(const int* __restrict__ src,
                                                        const int* __restrict__ dst,
                                                        int* __restrict__ bin_cursor,
                                                        unsigned* __restrict__ entries) {
    __shared__ int cnt[NB];    // 6.3 KB
    __shared__ int gcur[NB];   // 6.3 KB: global base, then running cursor
    for (int i = threadIdx.x; i < NB; i += 256) cnt[i] = 0;
    __syncthreads();
    const int base = blockIdx.x * 8192;
#pragma unroll 4
    for (int k = 0; k < 32; ++k) {
        int e = base + k * 256 + threadIdx.x;
        if (e < NE) atomicAdd(&cnt[src[e] >> 6], 1);
    }
    __syncthreads();
    for (int i = threadIdx.x; i < NB; i += 256) {
        int c = cnt[i];
        gcur[i] = c ? atomicAdd(&bin_cursor[i], c) : 0;
    }
    __syncthreads();
#pragma unroll 4
    for (int k = 0; k < 32; ++k) {
        int e = base + k * 256 + threadIdx.x;
        if (e < NE) {
            int s = src[e];
            int b = s >> 6;
            int pos = atomicAdd(&gcur[b], 1);
            entries[pos] = ((unsigned)(s & 63) << 17) | (unsigned)dst[e];
        }
    }
}

// ---------------------------------------------------------------------------
// Fused per-bin segment-max: one block per 64-node bin, max-accumulator in
// LDS (64 x 128 fp32 = 32 KB -> 5 blocks/CU). Float max via int/uint atomic
// ordering trick (finite inputs). Feat layout permuted (f -> (f&1)*64+(f>>1))
// so each lane's two atomics hit bank = lane%32 with 2 lanes/bank (free).
// Untouched rows stay -inf -> written as 0 (empty-node semantics).
// ---------------------------------------------------------------------------
#define UNR 8
__global__ __launch_bounds__(256) void agg_bin_kernel(const float* __restrict__ H,
                                                      const int* __restrict__ offsets,
                                                      const unsigned* __restrict__ entries,
                                                      float* __restrict__ agg) {
    __shared__ float acc[BIN_NODES * DD];   // 32 KB, permuted feat layout
    const int t = threadIdx.x;
    const int lane = t & 63;
    const int wid = t >> 6;
    const int b = blockIdx.x;

    const float ninf = -INFINITY;
    float4 n4 = make_float4(ninf, ninf, ninf, ninf);
    for (int i = t; i < BIN_NODES * DD / 4; i += 256) ((float4*)acc)[i] = n4;
    __syncthreads();

    const int beg = offsets[b];
    const int end = offsets[b + 1];

    for (int i = beg + wid * UNR; i < end; i += 4 * UNR) {
        unsigned e[UNR];
        float2 v[UNR];
#pragma unroll
        for (int k = 0; k < UNR; ++k) {
            int idx = i + k;
            if (idx >= end) idx = end - 1;   // dup last edge: max is idempotent
            e[k] = entries[idx];
        }
#pragma unroll
        for (int k = 0; k < UNR; ++k)
            v[k] = *(const float2*)(H + (size_t)(e[k] & 0x1FFFFu) * DD + lane * 2);
#pragma unroll
        for (int k = 0; k < UNR; ++k) {
            int loc = (int)(e[k] >> 17);
            float* p0 = &acc[loc * DD + lane];        // feat 2*lane
            float* p1 = &acc[loc * DD + 64 + lane];   // feat 2*lane+1
            if (v[k].x >= 0.0f) atomicMax((int*)p0, __float_as_int(v[k].x));
            else                atomicMin((unsigned*)p0, __float_as_uint(v[k].x));
            if (v[k].y >= 0.0f) atomicMax((int*)p1, __float_as_int(v[k].y));
            else                atomicMin((unsigned*)p1, __float_as_uint(v[k].y));
        }
    }
    __syncthreads();

    for (int n = wid; n < BIN_NODES; n += 4) {
        int node = b * BIN_NODES + n;
        if (node < NN) {
            float x = acc[n * DD + lane];
            float y = acc[n * DD + 64 + lane];
            if (x == ninf) x = 0.0f;
            if (y == ninf) y = 0.0f;
            *(float2*)(agg + (size_t)node * DD + lane * 2) = make_float2(x, y);
        }
    }
}

// ---------------------------------------------------------------------------
// out[i,o] = b[o] + sum_d H[i,d]*W[o,d] + sum_d agg[i,d]*W[o,128+d]
// agg stored IN-PLACE in `out`. Safe: block reads only its own 64 rows, all
// reads precede the final __syncthreads before its stores.
// ---------------------------------------------------------------------------
__global__ __launch_bounds__(256) void sage_matmul_kernel(
        const float* __restrict__ H,
        const float* __restrict__ W,      // [128][256] row-major
        const float* __restrict__ bias,   // [128]
        float* __restrict__ out) {        // in: agg, out: result  [NN][128]
    __shared__ float Xs[64][68];
    __shared__ float Ws[64][132];

    const int t = threadIdx.x;
    const int block_row = blockIdx.x * 64;
    const int tx = t & 15;
    const int ty = t >> 4;

    float acc[4][8];
#pragma unroll
    for (int r = 0; r < 4; ++r)
#pragma unroll
        for (int o = 0; o < 8; ++o) acc[r][o] = 0.0f;

#pragma unroll
    for (int chunk = 0; chunk < 4; ++chunk) {
        const int k0 = chunk * 64;
        const bool from_agg = (k0 >= 128);
        const int koff = from_agg ? (k0 - 128) : k0;
        const float* xbase = from_agg ? out : H;

#pragma unroll
        for (int j = 0; j < 4; ++j) {
            int e = j * 256 + t;
            int r = e >> 4;
            int c = (e & 15) << 2;
            int row = block_row + r;
            float4 v = make_float4(0.f, 0.f, 0.f, 0.f);
            if (row < NN)
                v = *(const float4*)(xbase + (size_t)row * DD + koff + c);
            *(float4*)&Xs[r][c] = v;
        }

#pragma unroll
        for (int j = 0; j < 8; ++j) {
            int e = j * 256 + t;
            int kc = (e & 15) << 2;
            int o = e >> 4;
            float4 w4 = *(const float4*)(W + o * 256 + k0 + kc);
            Ws[kc + 0][o] = w4.x;
            Ws[kc + 1][o] = w4.y;
            Ws[kc + 2][o] = w4.z;
            Ws[kc + 3][o] = w4.w;
        }
        __syncthreads();

        for (int k = 0; k < 64; ++k) {
            float xv[4];
#pragma unroll
            for (int r = 0; r < 4; ++r) xv[r] = Xs[ty * 4 + r][k];
            float4 wa = *(const float4*)&Ws[k][tx * 8];
            float4 wb = *(const float4*)&Ws[k][tx * 8 + 4];
            float wv[8] = {wa.x, wa.y, wa.z, wa.w, wb.x, wb.y, wb.z, wb.w};
#pragma unroll
            for (int r = 0; r < 4; ++r)
#pragma unroll
                for (int o = 0; o < 8; ++o)
                    acc[r][o] = fmaf(xv[r], wv[o], acc[r][o]);
        }
        __syncthreads();
    }

    float4 ba = *(const float4*)(bias + tx * 8);
    float4 bb = *(const float4*)(bias + tx * 8 + 4);
#pragma unroll
    for (int r = 0; r < 4; ++r) {
        int row = block_row + ty * 4 + r;
        if (row < NN) {
            float4 oa = make_float4(acc[r][0] + ba.x, acc[r][1] + ba.y,
                                    acc[r][2] + ba.z, acc[r][3] + ba.w);
            float4 ob = make_float4(acc[r][4] + bb.x, acc[r][5] + bb.y,
                                    acc[r][6] + bb.z, acc[r][7] + bb.w);
            *(float4*)(out + (size_t)row * DD + tx * 8) = oa;
            *(float4*)(out + (size_t)row * DD + tx * 8 + 4) = ob;
        }
    }
}

extern "C" void kernel_launch(void* const* d_in, const int* in_sizes, int n_in,
                              void* d_out, int out_size, void* d_ws, size_t ws_size,
                              hipStream_t stream) {
    const float* H   = (const float*)d_in[0];
    const int*   src = (const int*)d_in[1];
    const int*   dst = (const int*)d_in[2];
    const float* W   = (const float*)d_in[3];
    const float* b   = (const float*)d_in[4];
    float* out = (float*)d_out;

    int* ws            = (int*)d_ws;
    int* bin_counts    = ws + WS_COUNTS;
    int* bin_offsets   = ws + WS_OFFSETS;
    int* bin_cursor    = ws + WS_CURSOR;
    unsigned* entries  = (unsigned*)(ws + WS_ENTRIES);

    zero_bins_kernel<<<(NB + 255) / 256, 256, 0, stream>>>(bin_counts);
    bin_count_kernel<<<256, 256, 0, stream>>>(src, bin_counts);
    bin_scan_kernel<<<1, 1024, 0, stream>>>(bin_counts, bin_offsets, bin_cursor);
    partition_kernel<<<(NE + 8191) / 8192, 256, 0, stream>>>(src, dst, bin_cursor, entries);
    agg_bin_kernel<<<NB, 256, 0, stream>>>(H, bin_offsets, entries, out);
    sage_matmul_kernel<<<(NN + 63) / 64, 256, 0, stream>>>(H, W, b, out);
}

// Round 4
// 299.785 us; speedup vs baseline: 14.2557x; 1.2732x over previous
//
#include <hip/hip_runtime.h>
#include <math.h>

#define NN 100000
#define NE 1600000
#define DD 128          // D_IN == D_OUT
#define NB 3125         // bins of 32 nodes (100000 = 32*3125 exactly)
#define BIN_NODES 32

// ---------------------------------------------------------------------------
// d_ws layout (int32 units), total ~32.2 MB:
//   Hb      [NN*DD bf16]   @ WS_HB       (25.6 MB)
//   Wb      [128*256 bf16] @ WS_WB       (64 KB)
//   counts  [NB]           @ WS_COUNTS
//   offsets [NB+1]         @ WS_OFFSETS
//   cursor  [NB]           @ WS_CURSOR
//   entries [NE]           @ WS_ENTRIES  (6.4 MB; packed (src&31)<<17 | dst)
// ---------------------------------------------------------------------------
#define WS_HB      0
#define WS_WB      (NN * DD / 2)                  // 6,400,000
#define WS_COUNTS  (WS_WB + 128 * 256 / 2)        // +16384
#define WS_OFFSETS (WS_COUNTS + NB)
#define WS_CURSOR  (WS_OFFSETS + NB + 1)
#define WS_ENTRIES (WS_CURSOR + NB + 1)

typedef __attribute__((ext_vector_type(8))) __bf16 bf8_t;
typedef __attribute__((ext_vector_type(4))) float f4_t;

// RNE float->bf16 (finite inputs only)
__device__ __forceinline__ unsigned short f2bf(float f) {
    unsigned u = __float_as_uint(f);
    u += 0x7FFFu + ((u >> 16) & 1u);
    return (unsigned short)(u >> 16);
}

// ---------------------------------------------------------------------------
// fp32 -> bf16 bulk convert: each thread does 8 elems (32B read, 16B write)
// ---------------------------------------------------------------------------
__global__ __launch_bounds__(256) void conv_bf16_kernel(const float* __restrict__ src,
                                                        uint4* __restrict__ dst,
                                                        int n8) {
    int i = blockIdx.x * 256 + threadIdx.x;
    if (i >= n8) return;
    const float4* s = (const float4*)src + (size_t)i * 2;
    float4 a = s[0], b = s[1];
    uint4 o;
    o.x = (unsigned)f2bf(a.x) | ((unsigned)f2bf(a.y) << 16);
    o.y = (unsigned)f2bf(a.z) | ((unsigned)f2bf(a.w) << 16);
    o.z = (unsigned)f2bf(b.x) | ((unsigned)f2bf(b.y) << 16);
    o.w = (unsigned)f2bf(b.z) | ((unsigned)f2bf(b.w) << 16);
    dst[i] = o;
}

__global__ __launch_bounds__(256) void zero_bins_kernel(int* __restrict__ counts) {
    int i = blockIdx.x * blockDim.x + threadIdx.x;
    if (i < NB) counts[i] = 0;
}

// LDS-privatized per-bin counting
__global__ __launch_bounds__(256) void bin_count_kernel(const int* __restrict__ src,
                                                        int* __restrict__ bin_counts) {
    __shared__ int cnt[NB];
    for (int i = threadIdx.x; i < NB; i += 256) cnt[i] = 0;
    __syncthreads();
    const int stride = gridDim.x * 256;
    for (int e = blockIdx.x * 256 + threadIdx.x; e < NE; e += stride)
        atomicAdd(&cnt[src[e] >> 5], 1);
    __syncthreads();
    for (int i = threadIdx.x; i < NB; i += 256) {
        int c = cnt[i];
        if (c) atomicAdd(&bin_counts[i], c);
    }
}

// Single-block exclusive scan over NB bins (4 tiles of 1024).
__global__ __launch_bounds__(1024) void bin_scan_kernel(const int* __restrict__ counts,
                                                        int* __restrict__ offsets,
                                                        int* __restrict__ cursor) {
    __shared__ int wsum[16];
    __shared__ int carry_s;
    const int t = threadIdx.x;
    const int lane = t & 63;
    const int w = t >> 6;
    if (t == 0) carry_s = 0;
    __syncthreads();
    for (int base = 0; base < NB; base += 1024) {
        int i = base + t;
        int v = (i < NB) ? counts[i] : 0;
        int incl = v;
#pragma unroll
        for (int off = 1; off < 64; off <<= 1) {
            int y = __shfl_up(incl, off, 64);
            if (lane >= off) incl += y;
        }
        if (lane == 63) wsum[w] = incl;
        __syncthreads();
        int wpre = 0;
#pragma unroll
        for (int k = 0; k < 16; ++k) wpre += (k < w) ? wsum[k] : 0;
        int carry = carry_s;
        int excl = carry + wpre + incl - v;
        if (i < NB) { offsets[i] = excl; cursor[i] = excl; }
        __syncthreads();
        if (t == 1023) carry_s = carry + wpre + incl;
        __syncthreads();
    }
    if (t == 0) offsets[NB] = carry_s;   // == NE
}

// Partition edges into per-bin segments; per-block per-bin runs appended via
// one global atomic per (block,bin) -> clustered writes.
__global__ __launch_bounds__(256) void partition_kernel(const int* __restrict__ src,
                                                        const int* __restrict__ dst,
                                                        int* __restrict__ bin_cursor,
                                                        unsigned* __restrict__ entries) {
    __shared__ int cnt[NB];    // 12.5 KB
    __shared__ int gcur[NB];   // 12.5 KB
    for (int i = threadIdx.x; i < NB; i += 256) cnt[i] = 0;
    __syncthreads();
    const int base = blockIdx.x * 8192;
#pragma unroll 4
    for (int k = 0; k < 32; ++k) {
        int e = base + k * 256 + threadIdx.x;
        if (e < NE) atomicAdd(&cnt[src[e] >> 5], 1);
    }
    __syncthreads();
    for (int i = threadIdx.x; i < NB; i += 256) {
        int c = cnt[i];
        gcur[i] = c ? atomicAdd(&bin_cursor[i], c) : 0;
    }
    __syncthreads();
#pragma unroll 4
    for (int k = 0; k < 32; ++k) {
        int e = base + k * 256 + threadIdx.x;
        if (e < NE) {
            int s = src[e];
            int b = s >> 5;
            int pos = atomicAdd(&gcur[b], 1);
            entries[pos] = ((unsigned)(s & 31) << 17) | (unsigned)dst[e];
        }
    }
}

// ---------------------------------------------------------------------------
// Per-bin segment-max: one block per 32-node bin, fp32 max-acc in LDS (16 KB
// -> 8 blocks/CU). Gather from bf16 H: 4B/lane = 256B/row/wave. LDS atomic
// max via int/uint ordering trick; permuted feat layout -> 2 lanes/bank (free).
// ---------------------------------------------------------------------------
#define UNR 8
__global__ __launch_bounds__(256) void agg_bin_kernel(const unsigned short* __restrict__ Hb,
                                                      const int* __restrict__ offsets,
                                                      const unsigned* __restrict__ entries,
                                                      float* __restrict__ agg) {
    __shared__ float acc[BIN_NODES * DD];   // 16 KB
    const int t = threadIdx.x;
    const int lane = t & 63;
    const int wid = t >> 6;
    const int b = blockIdx.x;

    const float ninf = -INFINITY;
    float4 n4 = make_float4(ninf, ninf, ninf, ninf);
    for (int i = t; i < BIN_NODES * DD / 4; i += 256) ((float4*)acc)[i] = n4;
    __syncthreads();

    const int beg = offsets[b];
    const int end = offsets[b + 1];

    for (int i = beg + wid * UNR; i < end; i += 4 * UNR) {
        unsigned e[UNR];
        unsigned v[UNR];
#pragma unroll
        for (int k = 0; k < UNR; ++k) {
            int idx = i + k;
            if (idx >= end) idx = end - 1;   // dup last: max is idempotent
            e[k] = entries[idx];
        }
#pragma unroll
        for (int k = 0; k < UNR; ++k)
            v[k] = *(const unsigned*)(Hb + (size_t)(e[k] & 0x1FFFFu) * DD + lane * 2);
#pragma unroll
        for (int k = 0; k < UNR; ++k) {
            int loc = (int)(e[k] >> 17);
            float x = __uint_as_float(v[k] << 16);          // feat 2*lane
            float y = __uint_as_float(v[k] & 0xFFFF0000u);  // feat 2*lane+1
            float* p0 = &acc[loc * DD + lane];
            float* p1 = &acc[loc * DD + 64 + lane];
            if (x >= 0.0f) atomicMax((int*)p0, __float_as_int(x));
            else           atomicMin((unsigned*)p0, __float_as_uint(x));
            if (y >= 0.0f) atomicMax((int*)p1, __float_as_int(y));
            else           atomicMin((unsigned*)p1, __float_as_uint(y));
        }
    }
    __syncthreads();

    for (int n = wid; n < BIN_NODES; n += 4) {
        int node = b * BIN_NODES + n;
        float x = acc[n * DD + lane];
        float y = acc[n * DD + 64 + lane];
        if (x == ninf) x = 0.0f;
        if (y == ninf) y = 0.0f;
        *(float2*)(agg + (size_t)node * DD + lane * 2) = make_float2(x, y);
    }
}

// ---------------------------------------------------------------------------
// bf16 MFMA matmul: out[i,o] = b[o] + sum_k X[i,k]*W[o,k], X = [Hb | agg].
// agg read fp32 from d_out (in-place; all global reads precede stores within
// the owning block). Block: 64 rows x 128 outs, 4 waves; wave = 16 rows, 8
// out-tiles of 16x16x32 MFMA; K = 256 in 4 chunks of 64.
// Frag layouts (m89/m91-verified): A[m=lane&15][k=quad*8+j],
// B[k=quad*8+j][n=lane&15], C/D row=quad*4+reg, col=lane&15.
// ---------------------------------------------------------------------------
#define XP 72   // LDS row pitch (bf16 elems): 144B -> 2-way bank alias (free)
__global__ __launch_bounds__(256) void mfma_matmul_kernel(
        const unsigned short* __restrict__ Hb,   // [NN][128] bf16
        const unsigned short* __restrict__ Wb,   // [128][256] bf16
        const float* __restrict__ bias,          // [128]
        float* __restrict__ out) {               // in: agg fp32, out: result
    __shared__ unsigned short Xs[64 * XP];       // 9.2 KB
    __shared__ unsigned short Ws[128 * XP];      // 18.4 KB
    const int t = threadIdx.x;
    const int lane = t & 63;
    const int w = t >> 6;
    const int quad = lane >> 4;
    const int l16 = lane & 15;
    const int blockrow = blockIdx.x * 64;

    f4_t acc[8] = {};

    for (int c = 0; c < 4; ++c) {
        const int k0 = c * 64;
        if (c < 2) {
            // X chunk from Hb (bf16): 64 rows x 64 k = 512 x 16B segs
            int seg = t & 7, r0 = t >> 3;        // r0: 0..31
#pragma unroll
            for (int j = 0; j < 2; ++j) {
                int r = r0 + 32 * j;
                int row = blockrow + r;
                uint4 v = make_uint4(0, 0, 0, 0);
                if (row < NN)
                    v = *(const uint4*)(Hb + (size_t)row * DD + k0 + seg * 8);
                *(uint4*)&Xs[r * XP + seg * 8] = v;
            }
        } else {
            // X chunk from agg (fp32 in out), convert to bf16 in staging
            int seg = t & 15, r0 = t >> 4;       // r0: 0..15, seg: 4 floats
#pragma unroll
            for (int j = 0; j < 4; ++j) {
                int r = r0 + 16 * j;
                int row = blockrow + r;
                float4 v = make_float4(0.f, 0.f, 0.f, 0.f);
                if (row < NN)
                    v = *(const float4*)(out + (size_t)row * DD + (k0 - 128) + seg * 4);
                uint2 p;
                p.x = (unsigned)f2bf(v.x) | ((unsigned)f2bf(v.y) << 16);
                p.y = (unsigned)f2bf(v.z) | ((unsigned)f2bf(v.w) << 16);
                *(uint2*)&Xs[r * XP + seg * 4] = p;
            }
        }
        // W chunk: 128 rows x 64 k = 1024 x 16B segs
        {
            int seg = t & 7, o0 = t >> 3;        // o0: 0..31
#pragma unroll
            for (int j = 0; j < 4; ++j) {
                int o = o0 + 32 * j;
                uint4 v = *(const uint4*)(Wb + (size_t)o * 256 + k0 + seg * 8);
                *(uint4*)&Ws[o * XP + seg * 8] = v;
            }
        }
        __syncthreads();
#pragma unroll
        for (int kk = 0; kk < 64; kk += 32) {
            bf8_t a = *(const bf8_t*)&Xs[(w * 16 + l16) * XP + kk + quad * 8];
#pragma unroll
            for (int ot = 0; ot < 8; ++ot) {
                bf8_t bf = *(const bf8_t*)&Ws[(ot * 16 + l16) * XP + kk + quad * 8];
                acc[ot] = __builtin_amdgcn_mfma_f32_16x16x32_bf16(a, bf, acc[ot], 0, 0, 0);
            }
        }
        __syncthreads();
    }

    // epilogue: bias + store (after all reads of this block's agg rows)
#pragma unroll
    for (int ot = 0; ot < 8; ++ot) {
        float bv = bias[ot * 16 + l16];
#pragma unroll
        for (int reg = 0; reg < 4; ++reg) {
            int row = blockrow + w * 16 + quad * 4 + reg;
            if (row < NN)
                out[(size_t)row * DD + ot * 16 + l16] = acc[ot][reg] + bv;
        }
    }
}

extern "C" void kernel_launch(void* const* d_in, const int* in_sizes, int n_in,
                              void* d_out, int out_size, void* d_ws, size_t ws_size,
                              hipStream_t stream) {
    const float* H   = (const float*)d_in[0];
    const int*   src = (const int*)d_in[1];
    const int*   dst = (const int*)d_in[2];
    const float* W   = (const float*)d_in[3];
    const float* b   = (const float*)d_in[4];
    float* out = (float*)d_out;

    int* ws = (int*)d_ws;
    unsigned short* Hb      = (unsigned short*)(ws + WS_HB);
    unsigned short* Wb      = (unsigned short*)(ws + WS_WB);
    int*            counts  = ws + WS_COUNTS;
    int*            offsets = ws + WS_OFFSETS;
    int*            cursor  = ws + WS_CURSOR;
    unsigned*       entries = (unsigned*)(ws + WS_ENTRIES);

    const int h8 = NN * DD / 8;        // 1.6M
    const int w8 = 128 * 256 / 8;      // 4096
    conv_bf16_kernel<<<(h8 + 255) / 256, 256, 0, stream>>>(H, (uint4*)Hb, h8);
    conv_bf16_kernel<<<(w8 + 255) / 256, 256, 0, stream>>>(W, (uint4*)Wb, w8);

    zero_bins_kernel<<<(NB + 255) / 256, 256, 0, stream>>>(counts);
    bin_count_kernel<<<256, 256, 0, stream>>>(src, counts);
    bin_scan_kernel<<<1, 1024, 0, stream>>>(counts, offsets, cursor);
    partition_kernel<<<(NE + 8191) / 8192, 256, 0, stream>>>(src, dst, cursor, entries);

    agg_bin_kernel<<<NB, 256, 0, stream>>>(Hb, offsets, entries, out);
    mfma_matmul_kernel<<<(NN + 63) / 64, 256, 0, stream>>>(Hb, Wb, b, out);
}

// Round 5
// 269.378 us; speedup vs baseline: 15.8649x; 1.1129x over previous
//
#include <hip/hip_runtime.h>
#include <math.h>

#define NN 100000
#define NE 1600000
#define DD 128          // D_IN == D_OUT
#define NB 3125         // bins of 32 nodes (100000 = 32*3125)
#define CAP 704         // entries capacity per bin; Poisson(512) max@3125 bins ~ +5sigma=625

// ---------------------------------------------------------------------------
// d_ws layout (int32 units):
//   Hb      [NN*DD bf16]     @ WS_HB   (25.6 MB)
//   cursor  [NB]             @ WS_CUR
//   entries [NB*CAP]         @ WS_ENT  (8.8 MB; packed (src&31)<<17 | dst)
//   Ab      [NN*DD bf16]     @ WS_AB   (25.6 MB, only if ws_size allows)
// ---------------------------------------------------------------------------
#define WS_HB  0
#define WS_CUR 6400000
#define WS_ENT 6403128
#define WS_AB  8603128
#define WS_END_AB (WS_AB + 6400000)

typedef __attribute__((ext_vector_type(8))) __bf16 bf8_t;
typedef __attribute__((ext_vector_type(4))) float f4_t;

// RNE float->bf16 (finite inputs only)
__device__ __forceinline__ unsigned f2bf(float f) {
    unsigned u = __float_as_uint(f);
    u += 0x7FFFu + ((u >> 16) & 1u);
    return u >> 16;
}

// fp32 -> bf16 bulk convert: 8 elems/thread
__global__ __launch_bounds__(256) void conv_bf16_kernel(const float* __restrict__ src,
                                                        uint4* __restrict__ dst,
                                                        int n8) {
    int i = blockIdx.x * 256 + threadIdx.x;
    if (i >= n8) return;
    const float4* s = (const float4*)src + (size_t)i * 2;
    float4 a = s[0], b = s[1];
    uint4 o;
    o.x = f2bf(a.x) | (f2bf(a.y) << 16);
    o.y = f2bf(a.z) | (f2bf(a.w) << 16);
    o.z = f2bf(b.x) | (f2bf(b.y) << 16);
    o.w = f2bf(b.z) | (f2bf(b.w) << 16);
    dst[i] = o;
}

__global__ __launch_bounds__(256) void cursor_init_kernel(int* __restrict__ cursor) {
    int i = blockIdx.x * 256 + threadIdx.x;
    if (i < NB) cursor[i] = i * CAP;
}

// Single-pass partition: LDS per-bin count -> one global reserve per
// (block,bin) -> clustered scatter into fixed-capacity bin regions.
__global__ __launch_bounds__(256) void partition_kernel(const int* __restrict__ src,
                                                        const int* __restrict__ dst,
                                                        int* __restrict__ bin_cursor,
                                                        unsigned* __restrict__ entries) {
    __shared__ int cnt[NB];    // 12.5 KB
    __shared__ int gcur[NB];   // 12.5 KB
    const int t = threadIdx.x;
    for (int i = t; i < NB; i += 256) cnt[i] = 0;
    __syncthreads();
    const int base = blockIdx.x * 8192;
    int sv[32];
#pragma unroll
    for (int k = 0; k < 32; ++k) {
        int e = base + k * 256 + t;
        sv[k] = (e < NE) ? src[e] : -1;
        if (e < NE) atomicAdd(&cnt[sv[k] >> 5], 1);
    }
    __syncthreads();
    for (int i = t; i < NB; i += 256) {
        int c = cnt[i];
        gcur[i] = c ? atomicAdd(&bin_cursor[i], c) : 0;
    }
    __syncthreads();
#pragma unroll
    for (int k = 0; k < 32; ++k) {
        int e = base + k * 256 + t;
        if (e < NE) {
            int s = sv[k];
            int pos = atomicAdd(&gcur[s >> 5], 1);
            entries[pos] = ((unsigned)(s & 31) << 17) | (unsigned)dst[e];
        }
    }
}

// ---------------------------------------------------------------------------
// Atomic-free per-bin segment-max: counting-sort the bin's entries by local
// node in LDS, then each wave does whole nodes: register fmax over the
// node's contiguous neighbor list (4-wide MLP), one global write per node.
// LDS ~6 KB -> max occupancy. BF16OUT: emit packed bf16 (exact: max of
// bf16 values) to Ab; else fp32 float2 to agg (in d_out).
// ---------------------------------------------------------------------------
template <bool BF16OUT>
__global__ __launch_bounds__(256) void agg_sort_kernel(const unsigned short* __restrict__ Hb,
                                                       const int* __restrict__ bin_cursor,
                                                       const unsigned* __restrict__ entries,
                                                       unsigned* __restrict__ Ab,
                                                       float* __restrict__ aggf) {
    __shared__ unsigned raw[CAP];
    __shared__ unsigned sorted[CAP];
    __shared__ int cnt[32], base_s[32], cur[32];
    const int t = threadIdx.x;
    const int b = blockIdx.x;
    const int beg = b * CAP;
    const int n = bin_cursor[b] - beg;

    if (t < 32) cnt[t] = 0;
    __syncthreads();
    for (int i = t; i < n; i += 256) {
        unsigned e = entries[beg + i];
        raw[i] = e;
        atomicAdd(&cnt[e >> 17], 1);
    }
    __syncthreads();
    if (t < 32) {
        int v = cnt[t];
        int incl = v;
#pragma unroll
        for (int o = 1; o < 32; o <<= 1) {
            int y = __shfl_up(incl, o, 64);
            if (t >= o) incl += y;
        }
        base_s[t] = incl - v;
        cur[t] = incl - v;
    }
    __syncthreads();
    for (int i = t; i < n; i += 256) {
        unsigned e = raw[i];
        int pos = atomicAdd(&cur[e >> 17], 1);
        sorted[pos] = e & 0x1FFFFu;
    }
    __syncthreads();

    const int lane = t & 63;
    const int w = t >> 6;
#pragma unroll
    for (int q = 0; q < 8; ++q) {
        int ln = w * 8 + q;
        int s0 = base_s[ln];
        int e0 = s0 + cnt[ln];
        float mx = 0.f, my = 0.f;
        if (s0 < e0) {
            mx = -INFINITY; my = -INFINITY;
            int j = s0;
            for (; j + 4 <= e0; j += 4) {
                unsigned d0 = sorted[j], d1 = sorted[j + 1];
                unsigned d2 = sorted[j + 2], d3 = sorted[j + 3];
                unsigned v0 = *(const unsigned*)(Hb + (size_t)d0 * DD + lane * 2);
                unsigned v1 = *(const unsigned*)(Hb + (size_t)d1 * DD + lane * 2);
                unsigned v2 = *(const unsigned*)(Hb + (size_t)d2 * DD + lane * 2);
                unsigned v3 = *(const unsigned*)(Hb + (size_t)d3 * DD + lane * 2);
                float x0 = __uint_as_float(v0 << 16), y0 = __uint_as_float(v0 & 0xFFFF0000u);
                float x1 = __uint_as_float(v1 << 16), y1 = __uint_as_float(v1 & 0xFFFF0000u);
                float x2 = __uint_as_float(v2 << 16), y2 = __uint_as_float(v2 & 0xFFFF0000u);
                float x3 = __uint_as_float(v3 << 16), y3 = __uint_as_float(v3 & 0xFFFF0000u);
                mx = fmaxf(mx, fmaxf(fmaxf(x0, x1), fmaxf(x2, x3)));
                my = fmaxf(my, fmaxf(fmaxf(y0, y1), fmaxf(y2, y3)));
            }
            for (; j < e0; ++j) {
                unsigned d0 = sorted[j];
                unsigned v0 = *(const unsigned*)(Hb + (size_t)d0 * DD + lane * 2);
                mx = fmaxf(mx, __uint_as_float(v0 << 16));
                my = fmaxf(my, __uint_as_float(v0 & 0xFFFF0000u));
            }
        }
        int node = b * 32 + ln;
        if (BF16OUT) {
            // exact: mx/my are bf16-representable (or 0)
            unsigned pv = (__float_as_uint(mx) >> 16) | (__float_as_uint(my) & 0xFFFF0000u);
            Ab[(size_t)node * 64 + lane] = pv;
        } else {
            *(float2*)(aggf + (size_t)node * DD + lane * 2) = make_float2(mx, my);
        }
    }
}

// ---------------------------------------------------------------------------
// bf16 MFMA matmul: out[i,o] = b[o] + sum_k X[i,k]*W[o,k], X = [Hb | agg].
// W converted fp32->bf16 during LDS staging (L2-resident, no pre-pass).
// BF16AGG: agg read from Ab (bf16); else fp32 in-place from d_out (safe:
// per-block row ownership, all global reads precede stores).
// Frag layouts (m89/m91): A[m=lane&15][k=quad*8+j], B[k][n=lane&15],
// C/D row=quad*4+reg, col=lane&15.
// ---------------------------------------------------------------------------
#define XP 72   // LDS row pitch (bf16): 144B -> 2-way bank alias (free)
template <bool BF16AGG>
__global__ __launch_bounds__(256) void mfma_matmul_kernel(
        const unsigned short* __restrict__ Hb,   // [NN][128] bf16
        const unsigned short* __restrict__ Ab,   // [NN][128] bf16 (or null)
        const float* __restrict__ W,             // [128][256] fp32
        const float* __restrict__ bias,          // [128]
        float* __restrict__ out) {               // result [NN][128] (fp32 agg in !BF16AGG)
    __shared__ unsigned short Xs[64 * XP];       // 9.2 KB
    __shared__ unsigned short Ws[128 * XP];      // 18.4 KB
    const int t = threadIdx.x;
    const int lane = t & 63;
    const int w = t >> 6;
    const int quad = lane >> 4;
    const int l16 = lane & 15;
    const int blockrow = blockIdx.x * 64;

    f4_t acc[8] = {};

    for (int c = 0; c < 4; ++c) {
        const int k0 = c * 64;
        if (BF16AGG || c < 2) {
            const unsigned short* xb = (c < 2) ? Hb : Ab;
            const int koff = (c < 2) ? k0 : k0 - 128;
            int seg = t & 7, r0 = t >> 3;        // 8 segs x 8 bf16 = 64 k
#pragma unroll
            for (int j = 0; j < 2; ++j) {
                int r = r0 + 32 * j;
                int row = blockrow + r;
                uint4 v = make_uint4(0, 0, 0, 0);
                if (row < NN)
                    v = *(const uint4*)(xb + (size_t)row * DD + koff + seg * 8);
                *(uint4*)&Xs[r * XP + seg * 8] = v;
            }
        } else {
            // fp32 agg from out, convert while staging
            int seg = t & 15, r0 = t >> 4;
#pragma unroll
            for (int j = 0; j < 4; ++j) {
                int r = r0 + 16 * j;
                int row = blockrow + r;
                float4 v = make_float4(0.f, 0.f, 0.f, 0.f);
                if (row < NN)
                    v = *(const float4*)(out + (size_t)row * DD + (k0 - 128) + seg * 4);
                uint2 p;
                p.x = f2bf(v.x) | (f2bf(v.y) << 16);
                p.y = f2bf(v.z) | (f2bf(v.w) << 16);
                *(uint2*)&Xs[r * XP + seg * 4] = p;
            }
        }
        // W chunk: 128 o x 64 k fp32 -> bf16. 128x16 float4 tasks / 256 thr = 8
        {
            int seg = t & 15, o0 = t >> 4;
#pragma unroll
            for (int j = 0; j < 8; ++j) {
                int o = o0 + 16 * j;
                float4 wv = *(const float4*)(W + (size_t)o * 256 + k0 + seg * 4);
                uint2 p;
                p.x = f2bf(wv.x) | (f2bf(wv.y) << 16);
                p.y = f2bf(wv.z) | (f2bf(wv.w) << 16);
                *(uint2*)&Ws[o * XP + seg * 4] = p;
            }
        }
        __syncthreads();
#pragma unroll
        for (int kk = 0; kk < 64; kk += 32) {
            bf8_t a = *(const bf8_t*)&Xs[(w * 16 + l16) * XP + kk + quad * 8];
#pragma unroll
            for (int ot = 0; ot < 8; ++ot) {
                bf8_t bf = *(const bf8_t*)&Ws[(ot * 16 + l16) * XP + kk + quad * 8];
                acc[ot] = __builtin_amdgcn_mfma_f32_16x16x32_bf16(a, bf, acc[ot], 0, 0, 0);
            }
        }
        __syncthreads();
    }

#pragma unroll
    for (int ot = 0; ot < 8; ++ot) {
        float bv = bias[ot * 16 + l16];
#pragma unroll
        for (int reg = 0; reg < 4; ++reg) {
            int row = blockrow + w * 16 + quad * 4 + reg;
            if (row < NN)
                out[(size_t)row * DD + ot * 16 + l16] = acc[ot][reg] + bv;
        }
    }
}

extern "C" void kernel_launch(void* const* d_in, const int* in_sizes, int n_in,
                              void* d_out, int out_size, void* d_ws, size_t ws_size,
                              hipStream_t stream) {
    const float* H   = (const float*)d_in[0];
    const int*   src = (const int*)d_in[1];
    const int*   dst = (const int*)d_in[2];
    const float* W   = (const float*)d_in[3];
    const float* b   = (const float*)d_in[4];
    float* out = (float*)d_out;

    int* ws = (int*)d_ws;
    unsigned short* Hb      = (unsigned short*)(ws + WS_HB);
    int*            cursor  = ws + WS_CUR;
    unsigned*       entries = (unsigned*)(ws + WS_ENT);
    unsigned*       Ab      = (unsigned*)(ws + WS_AB);

    const bool use_ab = ws_size >= (size_t)WS_END_AB * 4;

    const int h8 = NN * DD / 8;   // 1.6M
    conv_bf16_kernel<<<(h8 + 255) / 256, 256, 0, stream>>>(H, (uint4*)Hb, h8);
    cursor_init_kernel<<<(NB + 255) / 256, 256, 0, stream>>>(cursor);
    partition_kernel<<<(NE + 8191) / 8192, 256, 0, stream>>>(src, dst, cursor, entries);

    if (use_ab) {
        agg_sort_kernel<true><<<NB, 256, 0, stream>>>(Hb, cursor, entries, Ab, out);
        mfma_matmul_kernel<true><<<(NN + 63) / 64, 256, 0, stream>>>(
            Hb, (const unsigned short*)Ab, W, b, out);
    } else {
        agg_sort_kernel<false><<<NB, 256, 0, stream>>>(Hb, cursor, entries, Ab, out);
        mfma_matmul_kernel<false><<<(NN + 63) / 64, 256, 0, stream>>>(
            Hb, (const unsigned short*)Ab, W, b, out);
    }
}

// Round 7
// 239.758 us; speedup vs baseline: 17.8249x; 1.1235x over previous
//
#include <hip/hip_runtime.h>
#include <math.h>

#define NN 100000
#define NE 1600000
#define DD 128          // D_IN == D_OUT
#define NB 1563         // 64-node bins: ceil(100000/64)
#define CAP 1280        // per-bin entry capacity; Poisson(1024) max over 1563 bins ~1147
#define PB 196          // partition blocks (8192 edges each)
#define CB 196          // conv blocks (grid-stride)

// ---------------------------------------------------------------------------
// d_ws layout (int32 units), total ~59.2 MB (round 5 proved ws >= 60 MB):
//   Hh      [NN*DD fp16]   @ WS_HH   (25.6 MB)
//   cursor  [NB]           @ WS_CUR
//   entries [NB*CAP]       @ WS_ENT  (8.0 MB; packed (src&63)<<17 | dst)
//   Ah      [NN*DD fp16]   @ WS_AH   (25.6 MB)
// ---------------------------------------------------------------------------
#define WS_HH  0
#define WS_CUR 6400000
#define WS_ENT (WS_CUR + NB)
#define WS_AH  (WS_ENT + NB * CAP)

typedef __attribute__((ext_vector_type(8))) _Float16 h8_t;
typedef __attribute__((ext_vector_type(2))) _Float16 h2_t;
typedef __attribute__((ext_vector_type(4))) float f4_t;

// packed fp32x2 -> fp16x2 (RNE via v_cvt)
__device__ __forceinline__ unsigned pk2h(float x, float y) {
    h2_t h;
    h.x = (_Float16)x;
    h.y = (_Float16)y;
    return *(unsigned*)&h;
}

__device__ __forceinline__ h2_t h2max(h2_t a, h2_t b) {
    return __builtin_elementwise_max(a, b);   // v_pk_max_f16
}

__global__ __launch_bounds__(1024) void cursor_init_kernel(int* __restrict__ cursor) {
    int i = blockIdx.x * 1024 + threadIdx.x;
    if (i < NB) cursor[i] = i * CAP;
}

// ---------------------------------------------------------------------------
// Fused prep: blocks [0,PB) partition edges into per-bin regions (LDS count ->
// one global reserve per (block,bin) -> clustered scatter); blocks [PB,PB+CB)
// convert H fp32 -> fp16 (grid-stride). The two populations overlap: conv is
// pure-memory, partition is atomic/LDS-bound.
// ---------------------------------------------------------------------------
__global__ __launch_bounds__(1024) void prep_kernel(const float* __restrict__ H,
                                                    const int* __restrict__ src,
                                                    const int* __restrict__ dst,
                                                    int* __restrict__ cursor,
                                                    unsigned* __restrict__ entries,
                                                    uint4* __restrict__ Hh4) {
    __shared__ int cnt[NB];    // 6.25 KB
    __shared__ int gcur[NB];   // 6.25 KB
    const int t = threadIdx.x;
    const int b = blockIdx.x;
    if (b < PB) {
        for (int i = t; i < NB; i += 1024) cnt[i] = 0;
        __syncthreads();
        const int base = b * 8192;
        int sv[8];
#pragma unroll
        for (int k = 0; k < 8; ++k) {
            int e = base + k * 1024 + t;
            sv[k] = (e < NE) ? src[e] : -1;
            if (sv[k] >= 0) atomicAdd(&cnt[sv[k] >> 6], 1);
        }
        __syncthreads();
        for (int i = t; i < NB; i += 1024) {
            int c = cnt[i];
            gcur[i] = c ? atomicAdd(&cursor[i], c) : 0;
        }
        __syncthreads();
#pragma unroll
        for (int k = 0; k < 8; ++k) {
            int e = base + k * 1024 + t;
            if (sv[k] >= 0) {
                int s = sv[k];
                int pos = atomicAdd(&gcur[s >> 6], 1);
                entries[pos] = ((unsigned)(s & 63) << 17) | (unsigned)dst[e];
            }
        }
    } else {
        const int nb = b - PB;
        const int n8 = NN * DD / 8;   // 1.6M tasks of 8 elems
        for (int i = nb * 1024 + t; i < n8; i += CB * 1024) {
            const float4* s = (const float4*)H + (size_t)i * 2;
            float4 a = s[0], c4 = s[1];
            uint4 o;
            o.x = pk2h(a.x, a.y);
            o.y = pk2h(a.z, a.w);
            o.z = pk2h(c4.x, c4.y);
            o.w = pk2h(c4.z, c4.w);
            Hh4[i] = o;
        }
    }
}

// ---------------------------------------------------------------------------
// Atomic-free per-bin segment-max: counting-sort the bin's entries by local
// node (64 counters, wave-0 shfl scan), then each wave processes whole nodes:
// packed v_pk_max_f16 over the node's contiguous neighbor list, one global
// write per node. LDS ~10.3 KB. fp16 max is exact on the fp16-converted H.
// ---------------------------------------------------------------------------
__global__ __launch_bounds__(256) void agg_kernel(const _Float16* __restrict__ Hh,
                                                  const int* __restrict__ cursor,
                                                  const unsigned* __restrict__ entries,
                                                  unsigned* __restrict__ Ah) {
    __shared__ unsigned raw[CAP];
    __shared__ unsigned sorted[CAP];
    __shared__ int cnt[64], base_s[64], cur[64];
    const int t = threadIdx.x;
    const int b = blockIdx.x;
    const int n = cursor[b] - b * CAP;

    if (t < 64) cnt[t] = 0;
    __syncthreads();
    for (int i = t; i < n; i += 256) {
        unsigned e = entries[b * CAP + i];
        raw[i] = e;
        atomicAdd(&cnt[e >> 17], 1);
    }
    __syncthreads();
    if (t < 64) {   // threads 0..63 == wave 0
        int v = cnt[t];
        int incl = v;
#pragma unroll
        for (int o = 1; o < 64; o <<= 1) {
            int y = __shfl_up(incl, o, 64);
            if (t >= o) incl += y;
        }
        base_s[t] = incl - v;
        cur[t] = incl - v;
    }
    __syncthreads();
    for (int i = t; i < n; i += 256) {
        unsigned e = raw[i];
        int pos = atomicAdd(&cur[e >> 17], 1);
        sorted[pos] = e & 0x1FFFFu;
    }
    __syncthreads();

    const int lane = t & 63;
    const int w = t >> 6;
#pragma unroll
    for (int q = 0; q < 16; ++q) {
        int ln = w * 16 + q;
        int s0 = base_s[ln];
        int e0 = s0 + cnt[ln];
        unsigned mu = 0xFC00FC00u;              // (-inf, -inf) fp16
        h2_t m = *(h2_t*)&mu;
        int j = s0;
        for (; j + 4 <= e0; j += 4) {
            unsigned d0 = sorted[j], d1 = sorted[j + 1];
            unsigned d2 = sorted[j + 2], d3 = sorted[j + 3];
            h2_t v0 = *(const h2_t*)(Hh + (size_t)d0 * DD + lane * 2);
            h2_t v1 = *(const h2_t*)(Hh + (size_t)d1 * DD + lane * 2);
            h2_t v2 = *(const h2_t*)(Hh + (size_t)d2 * DD + lane * 2);
            h2_t v3 = *(const h2_t*)(Hh + (size_t)d3 * DD + lane * 2);
            m = h2max(m, h2max(h2max(v0, v1), h2max(v2, v3)));
        }
        for (; j < e0; ++j) {
            h2_t v0 = *(const h2_t*)(Hh + (size_t)sorted[j] * DD + lane * 2);
            m = h2max(m, v0);
        }
        int node = b * 64 + ln;
        if (node < NN) {
            unsigned outv = (s0 < e0) ? *(unsigned*)&m : 0u;
            Ah[(size_t)node * 64 + lane] = outv;
        }
    }
}

// ---------------------------------------------------------------------------
// fp16 MFMA matmul: out[i,o] = b[o] + sum_k X[i,k]*W[o,k], X = [Hh | Ah].
// W converted fp32->fp16 during LDS staging (L2-resident). Block: 64 rows x
// 128 outs, 4 waves, 8 out-tiles of 16x16x32 MFMA, K=256 in 4 chunks of 64.
// Frag layouts (m89/m91, dtype-independent): A[m=lane&15][k=quad*8+j],
// B[k][n=lane&15], C/D row=quad*4+reg, col=lane&15.
// ---------------------------------------------------------------------------
#define XP 72   // LDS row pitch (fp16 elems): 144B -> 2-way bank alias (free)
__global__ __launch_bounds__(256) void mfma_matmul_kernel(
        const unsigned short* __restrict__ Hh,   // [NN][128] fp16
        const unsigned short* __restrict__ Ah,   // [NN][128] fp16
        const float* __restrict__ W,             // [128][256] fp32
        const float* __restrict__ bias,          // [128]
        float* __restrict__ out) {               // [NN][128] fp32
    __shared__ unsigned short Xs[64 * XP];       // 9.2 KB
    __shared__ unsigned short Ws[128 * XP];      // 18.4 KB
    const int t = threadIdx.x;
    const int lane = t & 63;
    const int w = t >> 6;
    const int quad = lane >> 4;
    const int l16 = lane & 15;
    const int blockrow = blockIdx.x * 64;

    f4_t acc[8] = {};

    for (int c = 0; c < 4; ++c) {
        const int k0 = c * 64;
        {
            const unsigned short* xb = (c < 2) ? Hh : Ah;
            const int koff = (c < 2) ? k0 : k0 - 128;
            int seg = t & 7, r0 = t >> 3;        // 8 segs x 8 fp16 = 64 k
#pragma unroll
            for (int j = 0; j < 2; ++j) {
                int r = r0 + 32 * j;
                int row = blockrow + r;
                uint4 v = make_uint4(0, 0, 0, 0);
                if (row < NN)
                    v = *(const uint4*)(xb + (size_t)row * DD + koff + seg * 8);
                *(uint4*)&Xs[r * XP + seg * 8] = v;
            }
        }
        {
            int seg = t & 15, o0 = t >> 4;
#pragma unroll
            for (int j = 0; j < 8; ++j) {
                int o = o0 + 16 * j;
                float4 wv = *(const float4*)(W + (size_t)o * 256 + k0 + seg * 4);
                uint2 p;
                p.x = pk2h(wv.x, wv.y);
                p.y = pk2h(wv.z, wv.w);
                *(uint2*)&Ws[o * XP + seg * 4] = p;
            }
        }
        __syncthreads();
#pragma unroll
        for (int kk = 0; kk < 64; kk += 32) {
            h8_t a = *(const h8_t*)&Xs[(w * 16 + l16) * XP + kk + quad * 8];
#pragma unroll
            for (int ot = 0; ot < 8; ++ot) {
                h8_t bf = *(const h8_t*)&Ws[(ot * 16 + l16) * XP + kk + quad * 8];
                acc[ot] = __builtin_amdgcn_mfma_f32_16x16x32_f16(a, bf, acc[ot], 0, 0, 0);
            }
        }
        __syncthreads();
    }

#pragma unroll
    for (int ot = 0; ot < 8; ++ot) {
        float bv = bias[ot * 16 + l16];
#pragma unroll
        for (int reg = 0; reg < 4; ++reg) {
            int row = blockrow + w * 16 + quad * 4 + reg;
            if (row < NN)
                out[(size_t)row * DD + ot * 16 + l16] = acc[ot][reg] + bv;
        }
    }
}

extern "C" void kernel_launch(void* const* d_in, const int* in_sizes, int n_in,
                              void* d_out, int out_size, void* d_ws, size_t ws_size,
                              hipStream_t stream) {
    const float* H   = (const float*)d_in[0];
    const int*   src = (const int*)d_in[1];
    const int*   dst = (const int*)d_in[2];
    const float* W   = (const float*)d_in[3];
    const float* b   = (const float*)d_in[4];
    float* out = (float*)d_out;

    int* ws = (int*)d_ws;
    unsigned short* Hh      = (unsigned short*)(ws + WS_HH);
    int*            cursor  = ws + WS_CUR;
    unsigned*       entries = (unsigned*)(ws + WS_ENT);
    unsigned*       Ah      = (unsigned*)(ws + WS_AH);

    cursor_init_kernel<<<2, 1024, 0, stream>>>(cursor);
    prep_kernel<<<PB + CB, 1024, 0, stream>>>(H, src, dst, cursor, entries, (uint4*)Hh);
    agg_kernel<<<NB, 256, 0, stream>>>((const _Float16*)Hh, cursor, entries, Ah);
    mfma_matmul_kernel<<<(NN + 63) / 64, 256, 0, stream>>>(
        Hh, (const unsigned short*)Ah, W, b, out);
}